// Round 1
// baseline (375.527 us; speedup 1.0000x reference)
//
#include <hip/hip_runtime.h>
#include <math.h>

#define DIMX 8
#define HDIM 128
#define S 32            // samples per workgroup
#define STR 132         // padded stride (floats) for per-sample 128-vectors; breaks 4-way bank conflicts
#define NT 256

// Fused dynamics kernel:
//   per sample: 2-layer tanh MLP grad g, directional 2nd deriv hvv = v^T H v,
//   force = -(Kx + Dv), out = force - g*(g.force + hvv)/(1+|g|^2)
__global__ __launch_bounds__(NT, 2)
void dyn_kernel(const float* __restrict__ X, const float* __restrict__ Km,
                const float* __restrict__ Dm, const float* __restrict__ W0,
                const float* __restrict__ b0, const float* __restrict__ W1,
                const float* __restrict__ b1, const float* __restrict__ W2,
                float* __restrict__ out)
{
    __shared__ float xt[S * 16];          // 512
    __shared__ float W0s[HDIM * DIMX];    // 1024
    __shared__ float b0s[HDIM], b1s[HDIM], W2s[HDIM];   // 384
    __shared__ float Ks[64], Ds[64];      // 128
    __shared__ float h0s[S * STR];        // 4224
    __shared__ float dh0s[S * STR];       // 4224 ; later aliased as gred (16*32*8=4096)
    __shared__ float a0s[S * STR];        // 4224 ; later aliased as u1
    __shared__ float hvv[S];
    __shared__ float gsm[S * DIMX], fsm[S * DIMX], alphas[S];

    const int tid = threadIdx.x;
    const long base = (long)blockIdx.x * S;   // first sample of this workgroup

    // ---------------- load weights + X tile ----------------
    {
        const float4* Xg = (const float4*)(X + base * 16);
        if (tid < 128) ((float4*)xt)[tid] = Xg[tid];               // 32 samples x 16 floats
        ((float4*)W0s)[tid] = ((const float4*)W0)[tid];            // 256 float4 == 1024 floats
        if (tid < 32)        ((float4*)b0s)[tid]       = ((const float4*)b0)[tid];
        else if (tid < 64)   ((float4*)b1s)[tid - 32]  = ((const float4*)b1)[tid - 32];
        else if (tid < 96)   ((float4*)W2s)[tid - 64]  = ((const float4*)W2)[tid - 64];
        else if (tid < 112)  ((float4*)Ks)[tid - 96]   = ((const float4*)Km)[tid - 96];
        else if (tid < 128)  ((float4*)Ds)[tid - 112]  = ((const float4*)Dm)[tid - 112];
        if (tid < S) hvv[tid] = 0.f;
    }
    __syncthreads();

    // ---------------- stage A: z0/dz0 -> h0, dh0, a0 ----------------
    {
        const int s = tid >> 3;        // 0..31
        const int p = tid & 7;         // 0..7
        const float* xv = &xt[s * 16];
        #pragma unroll
        for (int i = 0; i < 16; ++i) {
            const int k = p + 8 * i;
            const float* w = &W0s[k * 8];
            float z0 = b0s[k], dz0 = 0.f;
            #pragma unroll
            for (int d = 0; d < 8; ++d) {
                z0  = fmaf(w[d], xv[d], z0);
                dz0 = fmaf(w[d], xv[8 + d], dz0);
            }
            float h0 = tanhf(z0);
            float e  = 1.f - h0 * h0;
            h0s[s * STR + k]  = h0;
            dh0s[s * STR + k] = e * dz0;
            a0s[s * STR + k]  = -2.f * h0 * e * dz0 * dz0;
        }
    }
    __syncthreads();

    // ---------------- stage B: z1 = W1 h0 + b1 ; dz1 = W1 dh0 ; c1 = W1 a0 ----------------
    const int jg = tid & 15;           // output group: 8 outputs
    const int sg = tid >> 4;           // sample group: 2 samples
    const int s0 = sg * 2, s1 = s0 + 1;
    const int jbase = jg * 8;

    float accz[2][8], accd[2][8], accc[2][8];
    #pragma unroll
    for (int jj = 0; jj < 8; ++jj) {
        accz[0][jj] = accz[1][jj] = 0.f;
        accd[0][jj] = accd[1][jj] = 0.f;
        accc[0][jj] = accc[1][jj] = 0.f;
    }
    {
        const float4* h0p0  = (const float4*)&h0s[s0 * STR];
        const float4* h0p1  = (const float4*)&h0s[s1 * STR];
        const float4* dh0p0 = (const float4*)&dh0s[s0 * STR];
        const float4* dh0p1 = (const float4*)&dh0s[s1 * STR];
        const float4* a0p0  = (const float4*)&a0s[s0 * STR];
        const float4* a0p1  = (const float4*)&a0s[s1 * STR];
        for (int kb = 0; kb < 32; ++kb) {
            float4 ha = h0p0[kb],  hb = h0p1[kb];
            float4 da = dh0p0[kb], db = dh0p1[kb];
            float4 aa = a0p0[kb],  ab = a0p1[kb];
            #pragma unroll
            for (int jj = 0; jj < 8; ++jj) {
                float4 w = *(const float4*)&W1[(jbase + jj) * HDIM + kb * 4];
                accz[0][jj] = fmaf(w.x, ha.x, accz[0][jj]);
                accz[0][jj] = fmaf(w.y, ha.y, accz[0][jj]);
                accz[0][jj] = fmaf(w.z, ha.z, accz[0][jj]);
                accz[0][jj] = fmaf(w.w, ha.w, accz[0][jj]);
                accz[1][jj] = fmaf(w.x, hb.x, accz[1][jj]);
                accz[1][jj] = fmaf(w.y, hb.y, accz[1][jj]);
                accz[1][jj] = fmaf(w.z, hb.z, accz[1][jj]);
                accz[1][jj] = fmaf(w.w, hb.w, accz[1][jj]);
                accd[0][jj] = fmaf(w.x, da.x, accd[0][jj]);
                accd[0][jj] = fmaf(w.y, da.y, accd[0][jj]);
                accd[0][jj] = fmaf(w.z, da.z, accd[0][jj]);
                accd[0][jj] = fmaf(w.w, da.w, accd[0][jj]);
                accd[1][jj] = fmaf(w.x, db.x, accd[1][jj]);
                accd[1][jj] = fmaf(w.y, db.y, accd[1][jj]);
                accd[1][jj] = fmaf(w.z, db.z, accd[1][jj]);
                accd[1][jj] = fmaf(w.w, db.w, accd[1][jj]);
                accc[0][jj] = fmaf(w.x, aa.x, accc[0][jj]);
                accc[0][jj] = fmaf(w.y, aa.y, accc[0][jj]);
                accc[0][jj] = fmaf(w.z, aa.z, accc[0][jj]);
                accc[0][jj] = fmaf(w.w, aa.w, accc[0][jj]);
                accc[1][jj] = fmaf(w.x, ab.x, accc[1][jj]);
                accc[1][jj] = fmaf(w.y, ab.y, accc[1][jj]);
                accc[1][jj] = fmaf(w.z, ab.z, accc[1][jj]);
                accc[1][jj] = fmaf(w.w, ab.w, accc[1][jj]);
            }
        }
    }
    __syncthreads();   // everyone done READING dh0/a0 before we overwrite a0 with u1

    // ---------------- stage B epilogue: h1, u1, hvv ----------------
    float* u1s = a0s;  // alias (a0 is dead)
    {
        float hv0 = 0.f, hv1 = 0.f;
        #pragma unroll
        for (int jj = 0; jj < 8; ++jj) {
            const int j = jbase + jj;
            const float w2 = W2s[j], bb = b1s[j];
            float h1 = tanhf(accz[0][jj] + bb);
            float e1 = 1.f - h1 * h1;
            u1s[s0 * STR + j] = w2 * e1;
            hv0 += w2 * (e1 * accc[0][jj] - 2.f * h1 * e1 * accd[0][jj] * accd[0][jj]);
            float h1b = tanhf(accz[1][jj] + bb);
            float e1b = 1.f - h1b * h1b;
            u1s[s1 * STR + j] = w2 * e1b;
            hv1 += w2 * (e1b * accc[1][jj] - 2.f * h1b * e1b * accd[1][jj] * accd[1][jj]);
        }
        atomicAdd(&hvv[s0], hv0);
        atomicAdd(&hvv[s1], hv1);
    }
    __syncthreads();

    // ---------------- stage C: t = W1^T u1 (AXPY over rows), u0, partial g ----------------
    float* gred = dh0s;  // alias (dh0 is dead): layout [ig][s][d], 16*32*8 = 4096 floats
    {
        const int ig = jg;
        const int ibase = ig * 8;
        float t0[8], t1[8];
        #pragma unroll
        for (int ii = 0; ii < 8; ++ii) { t0[ii] = 0.f; t1[ii] = 0.f; }
        for (int j = 0; j < HDIM; ++j) {
            const float ua = u1s[s0 * STR + j];
            const float ub = u1s[s1 * STR + j];
            float4 wA = *(const float4*)&W1[j * HDIM + ibase];
            float4 wB = *(const float4*)&W1[j * HDIM + ibase + 4];
            t0[0] = fmaf(ua, wA.x, t0[0]);  t0[1] = fmaf(ua, wA.y, t0[1]);
            t0[2] = fmaf(ua, wA.z, t0[2]);  t0[3] = fmaf(ua, wA.w, t0[3]);
            t0[4] = fmaf(ua, wB.x, t0[4]);  t0[5] = fmaf(ua, wB.y, t0[5]);
            t0[6] = fmaf(ua, wB.z, t0[6]);  t0[7] = fmaf(ua, wB.w, t0[7]);
            t1[0] = fmaf(ub, wA.x, t1[0]);  t1[1] = fmaf(ub, wA.y, t1[1]);
            t1[2] = fmaf(ub, wA.z, t1[2]);  t1[3] = fmaf(ub, wA.w, t1[3]);
            t1[4] = fmaf(ub, wB.x, t1[4]);  t1[5] = fmaf(ub, wB.y, t1[5]);
            t1[6] = fmaf(ub, wB.z, t1[6]);  t1[7] = fmaf(ub, wB.w, t1[7]);
        }
        float gp0[8], gp1[8];
        #pragma unroll
        for (int d = 0; d < 8; ++d) { gp0[d] = 0.f; gp1[d] = 0.f; }
        #pragma unroll
        for (int ii = 0; ii < 8; ++ii) {
            const int i = ibase + ii;
            const float h0a = h0s[s0 * STR + i];
            const float h0b = h0s[s1 * STR + i];
            const float u0a = t0[ii] * (1.f - h0a * h0a);
            const float u0b = t1[ii] * (1.f - h0b * h0b);
            const float* w = &W0s[i * 8];
            #pragma unroll
            for (int d = 0; d < 8; ++d) {
                gp0[d] = fmaf(w[d], u0a, gp0[d]);
                gp1[d] = fmaf(w[d], u0b, gp1[d]);
            }
        }
        #pragma unroll
        for (int d = 0; d < 8; ++d) {
            gred[(ig * S + s0) * 8 + d] = gp0[d];
            gred[(ig * S + s1) * 8 + d] = gp1[d];
        }
    }
    __syncthreads();

    // ---------------- reduce g ; force ----------------
    {
        const int s = tid >> 3, d = tid & 7;
        float acc = 0.f;
        #pragma unroll
        for (int igg = 0; igg < 16; ++igg) acc += gred[(igg * S + s) * 8 + d];
        gsm[s * 8 + d] = acc;
        float f = 0.f;
        const float* xv = &xt[s * 16];
        const float* Kr = &Ks[d * 8];
        const float* Dr = &Ds[d * 8];
        #pragma unroll
        for (int k2 = 0; k2 < 8; ++k2) {
            f = fmaf(Kr[k2], xv[k2], f);
            f = fmaf(Dr[k2], xv[8 + k2], f);
        }
        fsm[s * 8 + d] = -f;
    }
    __syncthreads();

    if (tid < S) {
        float gf = 0.f, gg = 0.f;
        #pragma unroll
        for (int d = 0; d < 8; ++d) {
            const float gv = gsm[tid * 8 + d];
            gf = fmaf(gv, fsm[tid * 8 + d], gf);
            gg = fmaf(gv, gv, gg);
        }
        alphas[tid] = (gf + hvv[tid]) / (1.f + gg);
    }
    __syncthreads();

    {
        const int s = tid >> 3;
        out[base * 8 + tid] = fsm[tid] - gsm[tid] * alphas[s];
    }
}

extern "C" void kernel_launch(void* const* d_in, const int* in_sizes, int n_in,
                              void* d_out, int out_size, void* d_ws, size_t ws_size,
                              hipStream_t stream) {
    const float* X  = (const float*)d_in[0];
    const float* Km = (const float*)d_in[1];
    const float* Dm = (const float*)d_in[2];
    const float* W0 = (const float*)d_in[3];
    const float* b0 = (const float*)d_in[4];
    const float* W1 = (const float*)d_in[5];
    const float* b1 = (const float*)d_in[6];
    const float* W2 = (const float*)d_in[7];
    // d_in[8] = b2 (unused: cancels in grad/hessian/force)
    float* out = (float*)d_out;

    const int BATCH = in_sizes[0] / 16;        // 65536
    const int nblocks = BATCH / S;             // 2048
    dyn_kernel<<<nblocks, NT, 0, stream>>>(X, Km, Dm, W0, b0, W1, b1, W2, out);
}